// Round 4
// baseline (3191.661 us; speedup 1.0000x reference)
//
#include <hip/hip_runtime.h>
#include <math.h>

#define BB   2
#define NN   32768
#define DIN  768
#define DD   512
#define PP   16
#define MTOT (BB*NN)
#define NCHUNK 256
#define CHUNK  (NN/NCHUNK)   // 128
#define SCALE_INV_SQRT_D 0.04419417382415922f  // 1/sqrt(512)

typedef unsigned short u16;
typedef __attribute__((ext_vector_type(8))) short bf16x8;
typedef __attribute__((ext_vector_type(4))) float f32x4;

#define MFMA(a,b,c) __builtin_amdgcn_mfma_f32_16x16x32_bf16((a),(b),(c),0,0,0)

__device__ __forceinline__ unsigned pack2bf(float a, float b) {
  union { float f; unsigned u; } x{a}, y{b};
  unsigned ra = (x.u + 0x7FFFu + ((x.u >> 16) & 1u)) >> 16;
  unsigned rb = (y.u + 0x7FFFu + ((y.u >> 16) & 1u)) >> 16;
  return ra | (rb << 16);
}
__device__ __forceinline__ u16 f2bf(float a) {
  union { float f; unsigned u; } x{a};
  return (u16)((x.u + 0x7FFFu + ((x.u >> 16) & 1u)) >> 16);
}
__device__ __forceinline__ float bf2f(u16 u) {
  union { unsigned u; float f; } x; x.u = ((unsigned)u) << 16; return x.f;
}

__device__ __forceinline__ float block_reduce_sum_256(float v, float* sred) {
  #pragma unroll
  for (int off = 32; off; off >>= 1) v += __shfl_down(v, off);
  const int lane = threadIdx.x & 63, w = threadIdx.x >> 6;
  if (lane == 0) sred[w] = v;
  __syncthreads();
  float r = sred[0] + sred[1] + sred[2] + sred[3];
  __syncthreads();
  return r;
}

// ---------- W[768][512] fp32 -> Bf fragment layout: Bf[nf*24+ks][lane] ----------
// element: n = nf*16 + (lane&15), k = ks*32 + (lane>>4)*8 + j
__global__ __launch_bounds__(64) void bf_pack_kernel(const float* __restrict__ W,
                                                     uint4* __restrict__ Bf) {
  const int bid = blockIdx.x;            // nf*24 + ks, 768 blocks
  const int nf = bid / 24, ks = bid % 24;
  const int lane = threadIdx.x;
  const int n = nf*16 + (lane & 15);
  const int kb = ks*32 + (lane >> 4)*8;
  unsigned r0 = pack2bf(W[(size_t)(kb+0)*DD + n], W[(size_t)(kb+1)*DD + n]);
  unsigned r1 = pack2bf(W[(size_t)(kb+2)*DD + n], W[(size_t)(kb+3)*DD + n]);
  unsigned r2 = pack2bf(W[(size_t)(kb+4)*DD + n], W[(size_t)(kb+5)*DD + n]);
  unsigned r3 = pack2bf(W[(size_t)(kb+6)*DD + n], W[(size_t)(kb+7)*DD + n]);
  Bf[(size_t)bid*64 + lane] = make_uint4(r0, r1, r2, r3);
}

// ---------- normalize prototypes -> pn fp32 [16][512] ----------
__global__ __launch_bounds__(256) void proto_norm_kernel(
    const float* __restrict__ prot, float* __restrict__ pn) {
  __shared__ float sred[4];
  const int p = blockIdx.x, t = threadIdx.x;
  float2 v = *(const float2*)&prot[p*DD + 2*t];
  float ss = block_reduce_sum_256(v.x*v.x + v.y*v.y, sred);
  float sc = 1.f / fmaxf(sqrtf(ss), 1e-12f);
  *(float2*)&pn[p*DD + 2*t] = make_float2(v.x*sc, v.y*sc);
}

// ---------- Wpn = W·pn^T in B-fragment layout (p as n, 16 wide), + bpn ----------
// grid 25 x 64: blocks 0..23 -> Wpnb[ks][lane]; block 24 -> bpn[p]
__global__ __launch_bounds__(64) void wpn_pack_kernel(
    const float* __restrict__ W, const float* __restrict__ pn,
    const float* __restrict__ bias, uint4* __restrict__ Wpnb,
    float* __restrict__ bpn) {
  const int ks = blockIdx.x, lane = threadIdx.x;
  const int p = lane & 15;
  if (ks < 24) {
    float v[8];
    #pragma unroll
    for (int j = 0; j < 8; ++j) {
      const int k = ks*32 + (lane >> 4)*8 + j;
      const float* wr = W + (size_t)k * DD;
      const float* pr = pn + p * DD;
      float s = 0.f;
      for (int d = 0; d < DD; d += 4) {
        float4 a = *(const float4*)(wr + d);
        float4 b = *(const float4*)(pr + d);
        s += a.x*b.x + a.y*b.y + a.z*b.z + a.w*b.w;
      }
      v[j] = s;
    }
    Wpnb[ks*64 + lane] = make_uint4(pack2bf(v[0],v[1]), pack2bf(v[2],v[3]),
                                    pack2bf(v[4],v[5]), pack2bf(v[6],v[7]));
  } else {
    const int seg = lane >> 4;
    float s = 0.f;
    for (int d = seg*128; d < seg*128 + 128; ++d) s += bias[d] * pn[p*DD + d];
    s += __shfl_xor(s, 16);
    s += __shfl_xor(s, 32);
    if (lane < 16) bpn[lane] = s;
  }
}

// ---------- fused GEMM + scores + rnorm + expsum partials ----------
// grid 1024 (64-row slabs), 512 threads = 8 waves (2m x 4n), wave tile 32x128.
__global__ __launch_bounds__(512, 8) void gemm_kernel(
    const float* __restrict__ X, const uint4* __restrict__ Bf,
    const uint4* __restrict__ Wpnb, const float* __restrict__ bias,
    const float* __restrict__ bpn,
    u16* __restrict__ proj, float* __restrict__ wbuf,
    float* __restrict__ rnormbuf, float* __restrict__ espart) {
  __shared__ __align__(16) unsigned char Alds[2][8192];
  __shared__ float ssqp[64][4];
  __shared__ float espLDS[2][16];
  __shared__ float rnl[64];
  const int t = threadIdx.x, lane = t & 63;
  const int wid = t >> 6, wn = wid & 3, wm = wid >> 2;
  const int cl = lane & 15, cg = lane >> 4;
  const int m0 = blockIdx.x * 64;
  // A staging: thread covers row sr, k in [c8*8, c8*8+8)
  const int sr = t >> 3, c8 = t & 7;
  const int asl = ((((sr >> 4)*2 + (c8 >> 2))*64) + (c8 & 3)*16 + (sr & 15)) * 16;
  const float* gA = X + (size_t)(m0 + sr) * DIN + c8*8;

  f32x4 acc[2][8] = {};
  f32x4 sacc[2] = {};

  {
    float4 a0 = *(const float4*)(gA);
    float4 a1 = *(const float4*)(gA + 4);
    *(uint4*)(&Alds[0][asl]) = make_uint4(pack2bf(a0.x,a0.y), pack2bf(a0.z,a0.w),
                                          pack2bf(a1.x,a1.y), pack2bf(a1.z,a1.w));
  }
  for (int kt = 0; kt < 12; ++kt) {
    const int cur = kt & 1;
    float4 a0n, a1n;
    if (kt < 11) {
      a0n = *(const float4*)(gA + (kt+1)*64);
      a1n = *(const float4*)(gA + (kt+1)*64 + 4);
    }
    bf16x8 bfr[8], wf, af0, af1;
    #pragma unroll
    for (int j = 0; j < 8; ++j)
      bfr[j] = *(const bf16x8*)(Bf + ((size_t)((wn*8 + j)*24 + kt*2))*64 + lane);
    wf = *(const bf16x8*)(Wpnb + (kt*2)*64 + lane);
    __syncthreads();
    af0 = *(const bf16x8*)(&Alds[cur][(((wm*2+0)*2 + 0)*64 + lane)*16]);
    af1 = *(const bf16x8*)(&Alds[cur][(((wm*2+1)*2 + 0)*64 + lane)*16]);
    #pragma unroll
    for (int j = 0; j < 8; ++j) {
      acc[0][j] = MFMA(af0, bfr[j], acc[0][j]);
      acc[1][j] = MFMA(af1, bfr[j], acc[1][j]);
    }
    sacc[0] = MFMA(af0, wf, sacc[0]);
    sacc[1] = MFMA(af1, wf, sacc[1]);
    // half 1
    #pragma unroll
    for (int j = 0; j < 8; ++j)
      bfr[j] = *(const bf16x8*)(Bf + ((size_t)((wn*8 + j)*24 + kt*2 + 1))*64 + lane);
    wf = *(const bf16x8*)(Wpnb + (kt*2 + 1)*64 + lane);
    af0 = *(const bf16x8*)(&Alds[cur][(((wm*2+0)*2 + 1)*64 + lane)*16]);
    af1 = *(const bf16x8*)(&Alds[cur][(((wm*2+1)*2 + 1)*64 + lane)*16]);
    #pragma unroll
    for (int j = 0; j < 8; ++j) {
      acc[0][j] = MFMA(af0, bfr[j], acc[0][j]);
      acc[1][j] = MFMA(af1, bfr[j], acc[1][j]);
    }
    sacc[0] = MFMA(af0, wf, sacc[0]);
    sacc[1] = MFMA(af1, wf, sacc[1]);
    if (kt < 11) {
      *(uint4*)(&Alds[cur^1][asl]) = make_uint4(pack2bf(a0n.x,a0n.y), pack2bf(a0n.z,a0n.w),
                                                pack2bf(a1n.x,a1n.y), pack2bf(a1n.z,a1n.w));
    }
  }
  // ---- epilogue: bias, proj store, ssq, rnorm, scores, expsum partials
  float bv[8];
  #pragma unroll
  for (int j = 0; j < 8; ++j) bv[j] = bias[wn*128 + j*16 + cl];
  float ssql[2][4];
  #pragma unroll
  for (int m = 0; m < 2; ++m) {
    #pragma unroll
    for (int rr = 0; rr < 4; ++rr) {
      const int row = m0 + wm*32 + m*16 + cg*4 + rr;
      u16* pr = proj + (size_t)row * DD + wn*128 + cl;
      float sq = 0.f;
      #pragma unroll
      for (int j = 0; j < 8; ++j) {
        float val = acc[m][j][rr] + bv[j];
        pr[j*16] = f2bf(val);
        sq += val * val;
      }
      ssql[m][rr] = sq;
    }
  }
  #pragma unroll
  for (int m = 0; m < 2; ++m)
    #pragma unroll
    for (int rr = 0; rr < 4; ++rr) {
      float v = ssql[m][rr];
      v += __shfl_xor(v, 1); v += __shfl_xor(v, 2);
      v += __shfl_xor(v, 4); v += __shfl_xor(v, 8);
      if (cl == 0) ssqp[wm*32 + m*16 + cg*4 + rr][wn] = v;
    }
  __syncthreads();
  if (t < 64) {
    float ss = ssqp[t][0] + ssqp[t][1] + ssqp[t][2] + ssqp[t][3];
    float rn = 1.f / fmaxf(sqrtf(ss), 1e-12f);
    rnl[t] = rn;
    rnormbuf[m0 + t] = rn;
  }
  __syncthreads();
  if (wn == 0) {
    const int b = blockIdx.x >> 9;
    const int nb = m0 & (NN - 1);
    const float bp = bpn[cl];
    float esum = 0.f;
    #pragma unroll
    for (int m = 0; m < 2; ++m) {
      const int rowl = wm*32 + m*16 + cg*4;
      float4 scv;
      float sc0 = (sacc[m][0] + bp) * rnl[rowl+0] * SCALE_INV_SQRT_D;
      float sc1 = (sacc[m][1] + bp) * rnl[rowl+1] * SCALE_INV_SQRT_D;
      float sc2 = (sacc[m][2] + bp) * rnl[rowl+2] * SCALE_INV_SQRT_D;
      float sc3 = (sacc[m][3] + bp) * rnl[rowl+3] * SCALE_INV_SQRT_D;
      esum += expf(sc0) + expf(sc1) + expf(sc2) + expf(sc3);
      scv.x = sc0; scv.y = sc1; scv.z = sc2; scv.w = sc3;
      *(float4*)&wbuf[((size_t)(b*PP + cl))*NN + nb + rowl] = scv;
    }
    esum += __shfl_xor(esum, 16);
    esum += __shfl_xor(esum, 32);
    if (lane < 16) espLDS[wm][lane] = esum;
  }
  __syncthreads();
  if (t < 16) espart[blockIdx.x * 16 + t] = espLDS[0][t] + espLDS[1][t];
}

// ---------- reduce expsum partials -> iSrow[b*16+p]: grid 32 ----------
__global__ __launch_bounds__(256) void isum_kernel(const float* __restrict__ espart,
                                                   float* __restrict__ iSrow) {
  __shared__ float sred[4];
  const int rid = blockIdx.x, b = rid >> 4, p = rid & 15;
  float s = 0.f;
  for (int c = threadIdx.x; c < 512; c += 256)
    s += espart[(size_t)(b*512 + c)*16 + p];
  s = block_reduce_sum_256(s, sred);
  if (threadIdx.x == 0) iSrow[rid] = 1.f / s;
}

// ---------- attended (fused wsum): part[b][cid][d] ----------
__global__ __launch_bounds__(256) void attended_kernel(
    const u16* __restrict__ proj, const float* __restrict__ wbuf,
    const float* __restrict__ rnormbuf, const float* __restrict__ iSrow,
    float* __restrict__ part) {
  __shared__ float wl[CHUNK];
  __shared__ float iSl[PP];
  const int b = blockIdx.y, cid = blockIdx.x, t = threadIdx.x;
  const int nbase = cid * CHUNK;
  if (t < PP) iSl[t] = iSrow[b*PP + t];
  __syncthreads();
  if (t < CHUNK) {
    const int n = nbase + t;
    float s = 0.f;
    #pragma unroll
    for (int p = 0; p < PP; ++p)
      s += expf(wbuf[((size_t)(b*PP + p))*NN + n]) * iSl[p];
    wl[t] = s * rnormbuf[b*NN + n] * (1.f / PP);
  }
  __syncthreads();
  float a0 = 0.f, a1 = 0.f;
  const u16* pb = proj + (size_t)(b*NN + nbase) * DD + 2*t;
  #pragma unroll 8
  for (int n = 0; n < CHUNK; ++n) {
    unsigned uu = *(const unsigned*)(pb + (size_t)n * DD);
    float w = wl[n];
    a0 += w * bf2f((u16)uu);
    a1 += w * bf2f((u16)(uu >> 16));
  }
  *(float2*)&part[((size_t)(b*NCHUNK + cid))*DD + 2*t] = make_float2(a0, a1);
}

// ---------- reduce chunks -> featraw[b][d]: grid (4 dchunks, 2 b) ----------
__global__ __launch_bounds__(256) void featred_kernel(
    const float* __restrict__ part, float* __restrict__ featraw) {
  __shared__ float red[2][128];
  const int b = blockIdx.y, d0 = blockIdx.x * 128, t = threadIdx.x;
  const int dl = t & 127, half = t >> 7;
  float s = 0.f;
  for (int c = half*128; c < half*128 + 128; ++c)
    s += part[((size_t)(b*NCHUNK + c))*DD + d0 + dl];
  red[half][dl] = s;
  __syncthreads();
  if (t < 128) featraw[b*DD + d0 + t] = red[0][t] + red[1][t];
}

// ---------- final: normalize feats, logits, softmax, argmax, loss ----------
__global__ __launch_bounds__(256) void final_kernel(
    const float* __restrict__ frawL, const float* __restrict__ frawH,
    const float* __restrict__ textL, const float* __restrict__ textH,
    const int* __restrict__ label, float* __restrict__ out) {
  __shared__ float sred[4];
  const int t = threadIdx.x;
  float invL[2], invH[2];
  #pragma unroll
  for (int b = 0; b < 2; ++b) {
    float v = 0.f;
    for (int d = t; d < DD; d += 256) { float x = frawL[b*DD + d]; v += x*x; }
    float ss = block_reduce_sum_256(v, sred);
    invL[b] = 1.f / fmaxf(sqrtf(ss), 1e-12f);
    v = 0.f;
    for (int d = t; d < DD; d += 256) { float x = frawH[b*DD + d]; v += x*x; }
    ss = block_reduce_sum_256(v, sred);
    invH[b] = 1.f / fmaxf(sqrtf(ss), 1e-12f);
  }
  float lg[2][2];
  #pragma unroll
  for (int b = 0; b < 2; ++b)
    #pragma unroll
    for (int c = 0; c < 2; ++c) {
      float v = 0.f;
      for (int d = t; d < DD; d += 256)
        v += frawL[b*DD + d] * invL[b] * textL[c*DD + d]
           + frawH[b*DD + d] * invH[b] * textH[c*DD + d];
      lg[b][c] = block_reduce_sum_256(v, sred);
    }
  if (t == 0) {
    float loss = 0.f;
    #pragma unroll
    for (int b = 0; b < 2; ++b) {
      const float m  = fmaxf(lg[b][0], lg[b][1]);
      const float lse = m + logf(expf(lg[b][0]-m) + expf(lg[b][1]-m));
      out[b*2+0] = expf(lg[b][0]-lse); out[b*2+1] = expf(lg[b][1]-lse);
      out[4+b] = (lg[b][1] > lg[b][0]) ? 1.f : 0.f;
      loss += -(lg[b][label[b]] - lse);
    }
    out[6] = loss * 0.5f;
  }
}

extern "C" void kernel_launch(void* const* d_in, const int* in_sizes, int n_in,
                              void* d_out, int out_size, void* d_ws, size_t ws_size,
                              hipStream_t stream) {
  (void)in_sizes; (void)n_in; (void)out_size; (void)ws_size;
  const float* x_s  = (const float*)d_in[0];
  const float* x_l  = (const float*)d_in[2];
  const float* Wp   = (const float*)d_in[4];
  const float* bp   = (const float*)d_in[5];
  const float* prot = (const float*)d_in[6];
  const float* tL   = (const float*)d_in[7];
  const float* tH   = (const float*)d_in[8];
  const int*   label= (const int*)d_in[9];
  float* out = (float*)d_out;

  unsigned char* w8 = (unsigned char*)d_ws;
  u16*   proj   = (u16*)  (w8);                 // 67,108,864
  float* wbuf   = (float*)(w8 + 67108864);      //  4,194,304
  float* pn     = (float*)(w8 + 71303168);      //     32,768
  uint4* Bf     = (uint4*)(w8 + 71335936);      //    786,432
  uint4* Wpnb   = (uint4*)(w8 + 72122368);      //     24,576
  float* bpn    = (float*)(w8 + 72146944);      //        256
  float* rnormb = (float*)(w8 + 72147200);      //    262,144
  float* espart = (float*)(w8 + 72409344);      //     65,536
  float* iSrow  = (float*)(w8 + 72474880);      //        256
  float* part   = (float*)(w8 + 72475136);      //  1,048,576
  float* frawL  = (float*)(w8 + 73523712);      //      4,096
  float* frawH  = (float*)(w8 + 73527808);      //      4,096

  bf_pack_kernel<<<768, 64, 0, stream>>>(Wp, Bf);
  proto_norm_kernel<<<PP, 256, 0, stream>>>(prot, pn);
  wpn_pack_kernel<<<25, 64, 0, stream>>>(Wp, pn, bp, Wpnb, bpn);

  const float* xs[2] = {x_s, x_l};
  float* fts[2] = {frawL, frawH};
  for (int side = 0; side < 2; ++side) {
    gemm_kernel<<<MTOT/64, 512, 0, stream>>>(xs[side], Bf, Wpnb, bp, bpn,
                                             proj, wbuf, rnormb, espart);
    isum_kernel<<<BB*PP, 256, 0, stream>>>(espart, iSrow);
    attended_kernel<<<dim3(NCHUNK, BB), 256, 0, stream>>>(proj, wbuf, rnormb, iSrow, part);
    featred_kernel<<<dim3(4, BB), 256, 0, stream>>>(part, fts[side]);
  }
  final_kernel<<<1, 256, 0, stream>>>(frawL, frawH, tL, tH, label, out);
}

// Round 5
// 424.859 us; speedup vs baseline: 7.5123x; 7.5123x over previous
//
#include <hip/hip_runtime.h>
#include <math.h>

#define BB   2
#define NN   32768
#define DIN  768
#define DD   512
#define PP   16
#define MTOT (BB*NN)
#define NCHUNK 256
#define CHUNK  (NN/NCHUNK)   // 128
#define SCALE_INV_SQRT_D 0.04419417382415922f  // 1/sqrt(512)

typedef unsigned short u16;
typedef __attribute__((ext_vector_type(8))) short bf16x8;
typedef __attribute__((ext_vector_type(4))) float f32x4;

#define MFMA(a,b,c) __builtin_amdgcn_mfma_f32_16x16x32_bf16((a),(b),(c),0,0,0)

__device__ __forceinline__ unsigned pack2bf(float a, float b) {
  union { float f; unsigned u; } x{a}, y{b};
  unsigned ra = (x.u + 0x7FFFu + ((x.u >> 16) & 1u)) >> 16;
  unsigned rb = (y.u + 0x7FFFu + ((y.u >> 16) & 1u)) >> 16;
  return ra | (rb << 16);
}
__device__ __forceinline__ u16 f2bf(float a) {
  union { float f; unsigned u; } x{a};
  return (u16)((x.u + 0x7FFFu + ((x.u >> 16) & 1u)) >> 16);
}
__device__ __forceinline__ float bf2f(u16 u) {
  union { unsigned u; float f; } x; x.u = ((unsigned)u) << 16; return x.f;
}

__device__ __forceinline__ float block_reduce_sum_256(float v, float* sred) {
  #pragma unroll
  for (int off = 32; off; off >>= 1) v += __shfl_down(v, off);
  const int lane = threadIdx.x & 63, w = threadIdx.x >> 6;
  if (lane == 0) sred[w] = v;
  __syncthreads();
  float r = sred[0] + sred[1] + sred[2] + sred[3];
  __syncthreads();
  return r;
}

// ---------- W[768][512] fp32 -> Bf fragment layout: Bf[nf*24+ks][lane] ----------
// element: n = nf*16 + (lane&15), k = ks*32 + (lane>>4)*8 + j
__global__ __launch_bounds__(64) void bf_pack_kernel(const float* __restrict__ W,
                                                     uint4* __restrict__ Bf) {
  const int bid = blockIdx.x;            // nf*24 + ks, 768 blocks
  const int nf = bid / 24, ks = bid % 24;
  const int lane = threadIdx.x;
  const int n = nf*16 + (lane & 15);
  const int kb = ks*32 + (lane >> 4)*8;
  unsigned r0 = pack2bf(W[(size_t)(kb+0)*DD + n], W[(size_t)(kb+1)*DD + n]);
  unsigned r1 = pack2bf(W[(size_t)(kb+2)*DD + n], W[(size_t)(kb+3)*DD + n]);
  unsigned r2 = pack2bf(W[(size_t)(kb+4)*DD + n], W[(size_t)(kb+5)*DD + n]);
  unsigned r3 = pack2bf(W[(size_t)(kb+6)*DD + n], W[(size_t)(kb+7)*DD + n]);
  Bf[(size_t)bid*64 + lane] = make_uint4(r0, r1, r2, r3);
}

// ---------- normalize prototypes -> pn fp32 [16][512] ----------
__global__ __launch_bounds__(256) void proto_norm_kernel(
    const float* __restrict__ prot, float* __restrict__ pn) {
  __shared__ float sred[4];
  const int p = blockIdx.x, t = threadIdx.x;
  float2 v = *(const float2*)&prot[p*DD + 2*t];
  float ss = block_reduce_sum_256(v.x*v.x + v.y*v.y, sred);
  float sc = 1.f / fmaxf(sqrtf(ss), 1e-12f);
  *(float2*)&pn[p*DD + 2*t] = make_float2(v.x*sc, v.y*sc);
}

// ---------- Wpn = W·pn^T in B-fragment layout (p as n, 16 wide), + bpn ----------
__global__ __launch_bounds__(64) void wpn_pack_kernel(
    const float* __restrict__ W, const float* __restrict__ pn,
    const float* __restrict__ bias, uint4* __restrict__ Wpnb,
    float* __restrict__ bpn) {
  const int ks = blockIdx.x, lane = threadIdx.x;
  const int p = lane & 15;
  if (ks < 24) {
    float v[8];
    #pragma unroll
    for (int j = 0; j < 8; ++j) {
      const int k = ks*32 + (lane >> 4)*8 + j;
      const float* wr = W + (size_t)k * DD;
      const float* pr = pn + p * DD;
      float s = 0.f;
      for (int d = 0; d < DD; d += 4) {
        float4 a = *(const float4*)(wr + d);
        float4 b = *(const float4*)(pr + d);
        s += a.x*b.x + a.y*b.y + a.z*b.z + a.w*b.w;
      }
      v[j] = s;
    }
    Wpnb[ks*64 + lane] = make_uint4(pack2bf(v[0],v[1]), pack2bf(v[2],v[3]),
                                    pack2bf(v[4],v[5]), pack2bf(v[6],v[7]));
  } else {
    const int seg = lane >> 4;
    float s = 0.f;
    for (int d = seg*128; d < seg*128 + 128; ++d) s += bias[d] * pn[p*DD + d];
    s += __shfl_xor(s, 16);
    s += __shfl_xor(s, 32);
    if (lane < 16) bpn[lane] = s;
  }
}

// ---------- fused GEMM + scores + rnorm + expsum partials ----------
// grid 1024 (64-row slabs), 512 threads = 8 waves (2m x 4n), wave tile 32x128.
// launch_bounds (512,4): 128-VGPR cap, 4 waves/SIMD. (512,8) caused spill catastrophe.
__global__ __launch_bounds__(512, 4) void gemm_kernel(
    const float* __restrict__ X, const uint4* __restrict__ Bf,
    const uint4* __restrict__ Wpnb, const float* __restrict__ bias,
    const float* __restrict__ bpn,
    u16* __restrict__ proj, float* __restrict__ wbuf,
    float* __restrict__ rnormbuf, float* __restrict__ espart) {
  __shared__ __align__(16) unsigned char Alds[2][8192];
  __shared__ float ssqp[64][4];
  __shared__ float espLDS[2][16];
  __shared__ float rnl[64];
  const int t = threadIdx.x, lane = t & 63;
  const int wid = t >> 6, wn = wid & 3, wm = wid >> 2;
  const int cl = lane & 15, cg = lane >> 4;
  const int m0 = blockIdx.x * 64;
  // A staging: thread covers row sr, k in [c8*8, c8*8+8)
  const int sr = t >> 3, c8 = t & 7;
  const int f_ = (sr >> 4)*2 + (c8 >> 2);
  const int pos = (c8 & 3)*16 + (sr & 15);
  // XOR-swizzle bits 4-6 with bits 7-9 (symmetric on write & read) - kills 8-way write conflicts
  const int asl = (f_*1024 + pos*16) ^ (((pos >> 3) & 7) << 4);
  const int rdswz = (lane*16) ^ (((lane >> 3) & 7) << 4);
  const float* gA = X + (size_t)(m0 + sr) * DIN + c8*8;

  f32x4 acc[2][8] = {};
  f32x4 sacc[2] = {};

  {
    float4 a0 = *(const float4*)(gA);
    float4 a1 = *(const float4*)(gA + 4);
    *(uint4*)(&Alds[0][asl]) = make_uint4(pack2bf(a0.x,a0.y), pack2bf(a0.z,a0.w),
                                          pack2bf(a1.x,a1.y), pack2bf(a1.z,a1.w));
  }
  for (int kt = 0; kt < 12; ++kt) {
    const int cur = kt & 1;
    float4 a0n, a1n;
    if (kt < 11) {
      a0n = *(const float4*)(gA + (kt+1)*64);
      a1n = *(const float4*)(gA + (kt+1)*64 + 4);
    }
    __syncthreads();
    #pragma unroll
    for (int half = 0; half < 2; ++half) {
      const int ksx = kt*2 + half;
      bf16x8 af0 = *(const bf16x8*)(&Alds[cur][((wm*2+0)*2 + half)*1024 + rdswz]);
      bf16x8 af1 = *(const bf16x8*)(&Alds[cur][((wm*2+1)*2 + half)*1024 + rdswz]);
      // group 0: j = 0..3
      {
        bf16x8 b0 = *(const bf16x8*)(Bf + ((size_t)((wn*8 + 0)*24 + ksx))*64 + lane);
        bf16x8 b1 = *(const bf16x8*)(Bf + ((size_t)((wn*8 + 1)*24 + ksx))*64 + lane);
        bf16x8 b2 = *(const bf16x8*)(Bf + ((size_t)((wn*8 + 2)*24 + ksx))*64 + lane);
        bf16x8 b3 = *(const bf16x8*)(Bf + ((size_t)((wn*8 + 3)*24 + ksx))*64 + lane);
        acc[0][0] = MFMA(af0, b0, acc[0][0]); acc[1][0] = MFMA(af1, b0, acc[1][0]);
        acc[0][1] = MFMA(af0, b1, acc[0][1]); acc[1][1] = MFMA(af1, b1, acc[1][1]);
        acc[0][2] = MFMA(af0, b2, acc[0][2]); acc[1][2] = MFMA(af1, b2, acc[1][2]);
        acc[0][3] = MFMA(af0, b3, acc[0][3]); acc[1][3] = MFMA(af1, b3, acc[1][3]);
      }
      // group 1: j = 4..7 + Wpn
      {
        bf16x8 b4 = *(const bf16x8*)(Bf + ((size_t)((wn*8 + 4)*24 + ksx))*64 + lane);
        bf16x8 b5 = *(const bf16x8*)(Bf + ((size_t)((wn*8 + 5)*24 + ksx))*64 + lane);
        bf16x8 b6 = *(const bf16x8*)(Bf + ((size_t)((wn*8 + 6)*24 + ksx))*64 + lane);
        bf16x8 b7 = *(const bf16x8*)(Bf + ((size_t)((wn*8 + 7)*24 + ksx))*64 + lane);
        bf16x8 wf = *(const bf16x8*)(Wpnb + ksx*64 + lane);
        acc[0][4] = MFMA(af0, b4, acc[0][4]); acc[1][4] = MFMA(af1, b4, acc[1][4]);
        acc[0][5] = MFMA(af0, b5, acc[0][5]); acc[1][5] = MFMA(af1, b5, acc[1][5]);
        acc[0][6] = MFMA(af0, b6, acc[0][6]); acc[1][6] = MFMA(af1, b6, acc[1][6]);
        acc[0][7] = MFMA(af0, b7, acc[0][7]); acc[1][7] = MFMA(af1, b7, acc[1][7]);
        sacc[0] = MFMA(af0, wf, sacc[0]);     sacc[1] = MFMA(af1, wf, sacc[1]);
      }
    }
    if (kt < 11) {
      __syncthreads();
      *(uint4*)(&Alds[cur^1][asl]) = make_uint4(pack2bf(a0n.x,a0n.y), pack2bf(a0n.z,a0n.w),
                                                pack2bf(a1n.x,a1n.y), pack2bf(a1n.z,a1n.w));
    }
  }
  // ---- epilogue: bias, proj store, ssq, rnorm, scores, expsum partials
  float bv[8];
  #pragma unroll
  for (int j = 0; j < 8; ++j) bv[j] = bias[wn*128 + j*16 + cl];
  float ssql[2][4];
  #pragma unroll
  for (int m = 0; m < 2; ++m) {
    #pragma unroll
    for (int rr = 0; rr < 4; ++rr) {
      const int row = m0 + wm*32 + m*16 + cg*4 + rr;
      u16* pr = proj + (size_t)row * DD + wn*128 + cl;
      float sq = 0.f;
      #pragma unroll
      for (int j = 0; j < 8; ++j) {
        float val = acc[m][j][rr] + bv[j];
        pr[j*16] = f2bf(val);
        sq += val * val;
      }
      ssql[m][rr] = sq;
    }
  }
  #pragma unroll
  for (int m = 0; m < 2; ++m)
    #pragma unroll
    for (int rr = 0; rr < 4; ++rr) {
      float v = ssql[m][rr];
      v += __shfl_xor(v, 1); v += __shfl_xor(v, 2);
      v += __shfl_xor(v, 4); v += __shfl_xor(v, 8);
      if (cl == 0) ssqp[wm*32 + m*16 + cg*4 + rr][wn] = v;
    }
  __syncthreads();
  if (t < 64) {
    float ss = ssqp[t][0] + ssqp[t][1] + ssqp[t][2] + ssqp[t][3];
    float rn = 1.f / fmaxf(sqrtf(ss), 1e-12f);
    rnl[t] = rn;
    rnormbuf[m0 + t] = rn;
  }
  __syncthreads();
  if (wn == 0) {
    const int b = blockIdx.x >> 9;
    const int nb = m0 & (NN - 1);
    const float bp = bpn[cl];
    float esum = 0.f;
    #pragma unroll
    for (int m = 0; m < 2; ++m) {
      const int rowl = wm*32 + m*16 + cg*4;
      float4 scv;
      float sc0 = (sacc[m][0] + bp) * rnl[rowl+0] * SCALE_INV_SQRT_D;
      float sc1 = (sacc[m][1] + bp) * rnl[rowl+1] * SCALE_INV_SQRT_D;
      float sc2 = (sacc[m][2] + bp) * rnl[rowl+2] * SCALE_INV_SQRT_D;
      float sc3 = (sacc[m][3] + bp) * rnl[rowl+3] * SCALE_INV_SQRT_D;
      esum += expf(sc0) + expf(sc1) + expf(sc2) + expf(sc3);
      scv.x = sc0; scv.y = sc1; scv.z = sc2; scv.w = sc3;
      *(float4*)&wbuf[((size_t)(b*PP + cl))*NN + nb + rowl] = scv;
    }
    esum += __shfl_xor(esum, 16);
    esum += __shfl_xor(esum, 32);
    if (lane < 16) espLDS[wm][lane] = esum;
  }
  __syncthreads();
  if (t < 16) espart[blockIdx.x * 16 + t] = espLDS[0][t] + espLDS[1][t];
}

// ---------- reduce expsum partials -> iSrow[b*16+p]: grid 32 ----------
__global__ __launch_bounds__(256) void isum_kernel(const float* __restrict__ espart,
                                                   float* __restrict__ iSrow) {
  __shared__ float sred[4];
  const int rid = blockIdx.x, b = rid >> 4, p = rid & 15;
  float s = 0.f;
  for (int c = threadIdx.x; c < 512; c += 256)
    s += espart[(size_t)(b*512 + c)*16 + p];
  s = block_reduce_sum_256(s, sred);
  if (threadIdx.x == 0) iSrow[rid] = 1.f / s;
}

// ---------- attended (fused wsum): part[b][cid][d] ----------
__global__ __launch_bounds__(256) void attended_kernel(
    const u16* __restrict__ proj, const float* __restrict__ wbuf,
    const float* __restrict__ rnormbuf, const float* __restrict__ iSrow,
    float* __restrict__ part) {
  __shared__ float wl[CHUNK];
  __shared__ float iSl[PP];
  const int b = blockIdx.y, cid = blockIdx.x, t = threadIdx.x;
  const int nbase = cid * CHUNK;
  if (t < PP) iSl[t] = iSrow[b*PP + t];
  __syncthreads();
  if (t < CHUNK) {
    const int n = nbase + t;
    float s = 0.f;
    #pragma unroll
    for (int p = 0; p < PP; ++p)
      s += expf(wbuf[((size_t)(b*PP + p))*NN + n]) * iSl[p];
    wl[t] = s * rnormbuf[b*NN + n] * (1.f / PP);
  }
  __syncthreads();
  float a0 = 0.f, a1 = 0.f;
  const u16* pb = proj + (size_t)(b*NN + nbase) * DD + 2*t;
  #pragma unroll 8
  for (int n = 0; n < CHUNK; ++n) {
    unsigned uu = *(const unsigned*)(pb + (size_t)n * DD);
    float w = wl[n];
    a0 += w * bf2f((u16)uu);
    a1 += w * bf2f((u16)(uu >> 16));
  }
  *(float2*)&part[((size_t)(b*NCHUNK + cid))*DD + 2*t] = make_float2(a0, a1);
}

// ---------- reduce chunks -> featraw[b][d]: grid (4 dchunks, 2 b) ----------
__global__ __launch_bounds__(256) void featred_kernel(
    const float* __restrict__ part, float* __restrict__ featraw) {
  __shared__ float red[2][128];
  const int b = blockIdx.y, d0 = blockIdx.x * 128, t = threadIdx.x;
  const int dl = t & 127, half = t >> 7;
  float s = 0.f;
  for (int c = half*128; c < half*128 + 128; ++c)
    s += part[((size_t)(b*NCHUNK + c))*DD + d0 + dl];
  red[half][dl] = s;
  __syncthreads();
  if (t < 128) featraw[b*DD + d0 + t] = red[0][t] + red[1][t];
}

// ---------- final: normalize feats, logits, softmax, argmax, loss ----------
__global__ __launch_bounds__(256) void final_kernel(
    const float* __restrict__ frawL, const float* __restrict__ frawH,
    const float* __restrict__ textL, const float* __restrict__ textH,
    const int* __restrict__ label, float* __restrict__ out) {
  __shared__ float sred[4];
  const int t = threadIdx.x;
  float invL[2], invH[2];
  #pragma unroll
  for (int b = 0; b < 2; ++b) {
    float v = 0.f;
    for (int d = t; d < DD; d += 256) { float x = frawL[b*DD + d]; v += x*x; }
    float ss = block_reduce_sum_256(v, sred);
    invL[b] = 1.f / fmaxf(sqrtf(ss), 1e-12f);
    v = 0.f;
    for (int d = t; d < DD; d += 256) { float x = frawH[b*DD + d]; v += x*x; }
    ss = block_reduce_sum_256(v, sred);
    invH[b] = 1.f / fmaxf(sqrtf(ss), 1e-12f);
  }
  float lg[2][2];
  #pragma unroll
  for (int b = 0; b < 2; ++b)
    #pragma unroll
    for (int c = 0; c < 2; ++c) {
      float v = 0.f;
      for (int d = t; d < DD; d += 256)
        v += frawL[b*DD + d] * invL[b] * textL[c*DD + d]
           + frawH[b*DD + d] * invH[b] * textH[c*DD + d];
      lg[b][c] = block_reduce_sum_256(v, sred);
    }
  if (t == 0) {
    float loss = 0.f;
    #pragma unroll
    for (int b = 0; b < 2; ++b) {
      const float m  = fmaxf(lg[b][0], lg[b][1]);
      const float lse = m + logf(expf(lg[b][0]-m) + expf(lg[b][1]-m));
      out[b*2+0] = expf(lg[b][0]-lse); out[b*2+1] = expf(lg[b][1]-lse);
      out[4+b] = (lg[b][1] > lg[b][0]) ? 1.f : 0.f;
      loss += -(lg[b][label[b]] - lse);
    }
    out[6] = loss * 0.5f;
  }
}

extern "C" void kernel_launch(void* const* d_in, const int* in_sizes, int n_in,
                              void* d_out, int out_size, void* d_ws, size_t ws_size,
                              hipStream_t stream) {
  (void)in_sizes; (void)n_in; (void)out_size; (void)ws_size;
  const float* x_s  = (const float*)d_in[0];
  const float* x_l  = (const float*)d_in[2];
  const float* Wp   = (const float*)d_in[4];
  const float* bp   = (const float*)d_in[5];
  const float* prot = (const float*)d_in[6];
  const float* tL   = (const float*)d_in[7];
  const float* tH   = (const float*)d_in[8];
  const int*   label= (const int*)d_in[9];
  float* out = (float*)d_out;

  unsigned char* w8 = (unsigned char*)d_ws;
  u16*   proj   = (u16*)  (w8);                 // 67,108,864
  float* wbuf   = (float*)(w8 + 67108864);      //  4,194,304
  float* pn     = (float*)(w8 + 71303168);      //     32,768
  uint4* Bf     = (uint4*)(w8 + 71335936);      //    786,432
  uint4* Wpnb   = (uint4*)(w8 + 72122368);      //     24,576
  float* bpn    = (float*)(w8 + 72146944);      //        256
  float* rnormb = (float*)(w8 + 72147200);      //    262,144
  float* espart = (float*)(w8 + 72409344);      //     65,536
  float* iSrow  = (float*)(w8 + 72474880);      //        256
  float* part   = (float*)(w8 + 72475136);      //  1,048,576
  float* frawL  = (float*)(w8 + 73523712);      //      4,096
  float* frawH  = (float*)(w8 + 73527808);      //      4,096

  bf_pack_kernel<<<768, 64, 0, stream>>>(Wp, Bf);
  proto_norm_kernel<<<PP, 256, 0, stream>>>(prot, pn);
  wpn_pack_kernel<<<25, 64, 0, stream>>>(Wp, pn, bp, Wpnb, bpn);

  const float* xs[2] = {x_s, x_l};
  float* fts[2] = {frawL, frawH};
  for (int side = 0; side < 2; ++side) {
    gemm_kernel<<<MTOT/64, 512, 0, stream>>>(xs[side], Bf, Wpnb, bp, bpn,
                                             proj, wbuf, rnormb, espart);
    isum_kernel<<<BB*PP, 256, 0, stream>>>(espart, iSrow);
    attended_kernel<<<dim3(NCHUNK, BB), 256, 0, stream>>>(proj, wbuf, rnormb, iSrow, part);
    featred_kernel<<<dim3(4, BB), 256, 0, stream>>>(part, fts[side]);
  }
  final_kernel<<<1, 256, 0, stream>>>(frawL, frawH, tL, tH, label, out);
}